// Round 5
// baseline (129.104 us; speedup 1.0000x reference)
//
#include <hip/hip_runtime.h>
#include <math.h>

// Chamfer loss, two 16384x3 fp32 clouds.
// R9 = R8 DIAGNOSTIC RESUBMIT (R8 round lost to container infra failure).
// chamfer_main is ~38-40us vs a ~7us MFMA-pipe floor, hidden below the
// top-5 counter cutoff (the harness's 256MiB poison fill, ~40.4us). Run the
// IDENTICAL body twice (atomicMin idempotent -> absmax unchanged) to push
// main above the cutoff and capture its counters:
//   work-proportional (~78us) -> in-kernel dilation; read VALUBusy/MfmaUtil/
//       VGPR/Occupancy/LDS_CONFLICT/FETCH to name the pipe.
//   ~45-55us -> fixed per-dispatch overhead -> fuse/overlap next round.

typedef __attribute__((ext_vector_type(8)))  short bf16x8;   // 8 bf16 = 4 VGPR
typedef __attribute__((ext_vector_type(16))) float f32x16;   // MFMA C/D

#define S_SLICES 16   // col slices per direction; C = N/S = 1024 (32 KB LDS)

// Monotone float->uint map: a<b  <=>  enc(a)<enc(b).
__device__ __forceinline__ unsigned enc_f32(float f) {
    int b = __float_as_int(f);
    return (b >= 0) ? ((unsigned)b | 0x80000000u) : ~(unsigned)b;
}
__device__ __forceinline__ float dec_f32(unsigned k) {
    int b = (k & 0x80000000u) ? (int)(k & 0x7FFFFFFFu) : ~(int)k;
    return __int_as_float(b);
}

// fp32 -> bf16 (RNE), and back.
__device__ __forceinline__ unsigned short f2bf(float v) {
    unsigned u = __float_as_uint(v);
    u += 0x7FFFu + ((u >> 16) & 1u);
    return (unsigned short)(u >> 16);
}
__device__ __forceinline__ float bf2f(unsigned short b) {
    unsigned u = ((unsigned)b) << 16;
    return __uint_as_float(u);
}
__device__ __forceinline__ unsigned pk2(unsigned short lo, unsigned short hi) {
    return (unsigned)lo | ((unsigned)hi << 16);
}

// Build A-role and B-role K=16 fragments for every point of both clouds.
// d = |q|^2 + |p|^2 - 2(qh+ql).(ph+pl), all cross terms in the 16 K slots.
__global__ __launch_bounds__(256) void chamfer_prep(
    const float* __restrict__ state_x, const float* __restrict__ target,
    uint4* __restrict__ AfragS, uint4* __restrict__ AfragT,
    uint4* __restrict__ BfragS, uint4* __restrict__ BfragT,
    unsigned* __restrict__ mins_u, float* __restrict__ out, int N)
{
    const int p = blockIdx.x * 256 + threadIdx.x;     // [0, 2N)
    const float* src = (p < N) ? state_x : target;
    const int i = (p < N) ? p : p - N;

    const float x = src[3*i+0], y = src[3*i+1], z = src[3*i+2];
    const float n2 = fmaf(x, x, fmaf(y, y, z * z));

    const unsigned short hx = f2bf(x), hy = f2bf(y), hz = f2bf(z);
    const unsigned short lx = f2bf(x - bf2f(hx));
    const unsigned short ly = f2bf(y - bf2f(hy));
    const unsigned short lz = f2bf(z - bf2f(hz));
    const unsigned short mhx = f2bf(-2.0f*x), mhy = f2bf(-2.0f*y), mhz = f2bf(-2.0f*z);
    const unsigned short mlx = f2bf(-2.0f*x - bf2f(mhx));
    const unsigned short mly = f2bf(-2.0f*y - bf2f(mhy));
    const unsigned short mlz = f2bf(-2.0f*z - bf2f(mhz));
    const unsigned short hn = f2bf(n2);
    const unsigned short ln = f2bf(n2 - bf2f(hn));
    const unsigned short ONE = 0x3F80;

    // A-role: [mh(3), ml(3), mh(3), ml(3), hn, ln, 1, 1]
    uint4 A0 = make_uint4(pk2(mhx,mhy), pk2(mhz,mlx), pk2(mly,mlz), pk2(mhx,mhy));
    uint4 A1 = make_uint4(pk2(mhz,mlx), pk2(mly,mlz), pk2(hn,ln),   pk2(ONE,ONE));
    // B-role: [h(3), h(3), l(3), l(3), 1, 1, hn, ln]
    uint4 B0 = make_uint4(pk2(hx,hy), pk2(hz,hx), pk2(hy,hz), pk2(lx,ly));
    uint4 B1 = make_uint4(pk2(lz,lx), pk2(ly,lz), pk2(ONE,ONE), pk2(hn,ln));

    uint4* Aarr = (p < N) ? AfragS : AfragT;
    uint4* Barr = (p < N) ? BfragS : BfragT;
    Aarr[2*i+0] = A0;  Aarr[2*i+1] = A1;
    Barr[2*i+0] = B0;  Barr[2*i+1] = B1;

    mins_u[p] = 0xFFFFFFFFu;
    if (p == 0) *out = 0.0f;
}

// Main: identical to R7 except the whole body executes twice (diagnostic).
__global__ __launch_bounds__(256) void chamfer_main(
    const bf16x8* __restrict__ AfragS, const bf16x8* __restrict__ AfragT,
    const bf16x8* __restrict__ BfragS, const bf16x8* __restrict__ BfragT,
    unsigned* __restrict__ mins_u, int N, int S)
{
    const int tid  = threadIdx.x;
    const int lane = tid & 63;
    const int l31  = lane & 31;
    const int half = lane >> 5;
    const int w    = tid >> 6;

    const int bs = blockIdx.x / S;            // row-block (256 rows)
    const int s  = blockIdx.x % S;            // col slice
    const int qblk = bs * 256;                // [0, 2N), never straddles N

    const bf16x8* afr;
    const bf16x8* bfr;
    if (qblk < N) { afr = AfragT + (size_t)qblk * 2;       bfr = BfragS; }
    else          { afr = AfragS + (size_t)(qblk - N) * 2; bfr = BfragT; }

    const int C = N / S;                      // 1024 cols per slice

    __shared__ uint4 ldsB[2048];

    for (int rep = 0; rep < 2; ++rep) {       // DIAGNOSTIC x2 (idempotent)

    // ---- stage the B slice into LDS (2048 uint4 = 32 KB), coalesced ----
    {
        const uint4* src = (const uint4*)bfr + (size_t)(s * C) * 2;
        #pragma unroll
        for (int j = 0; j < 8; ++j)
            ldsB[tid + j * 256] = src[tid + j * 256];
    }
    __syncthreads();
    const bf16x8* lb = (const bf16x8*)ldsB;

    // A fragments for this wave's two 32-row tiles (rows w*64 .. w*64+63).
    const int r0 = w * 64;
    const bf16x8 av0 = afr[(r0 +      l31) * 2 + half];
    const bf16x8 av1 = afr[(r0 + 32 + l31) * 2 + half];

    const int boff = l31 * 2 + half;

    f32x16 racc0, racc1, zc;
    #pragma unroll
    for (int i = 0; i < 16; ++i) { racc0[i] = 3.0e38f; racc1[i] = 3.0e38f; zc[i] = 0.0f; }

    #pragma unroll 2
    for (int it = 0; it < C / 64; ++it) {
        const bf16x8 b0 = lb[it * 128 + boff];        // cols it*64    + l31
        const bf16x8 b1 = lb[it * 128 + 64 + boff];   // cols it*64+32 + l31
        {   // tile rows r0..r0+31
            f32x16 a0 = __builtin_amdgcn_mfma_f32_32x32x16_bf16(av0, b0, zc, 0, 0, 0);
            f32x16 a1 = __builtin_amdgcn_mfma_f32_32x32x16_bf16(av0, b1, zc, 0, 0, 0);
            #pragma unroll
            for (int i = 0; i < 16; ++i)
                racc0[i] = fminf(fminf(racc0[i], a0[i]), a1[i]);   // v_min3
        }
        {   // tile rows r0+32..r0+63
            f32x16 a0 = __builtin_amdgcn_mfma_f32_32x32x16_bf16(av1, b0, zc, 0, 0, 0);
            f32x16 a1 = __builtin_amdgcn_mfma_f32_32x32x16_bf16(av1, b1, zc, 0, 0, 0);
            #pragma unroll
            for (int i = 0; i < 16; ++i)
                racc1[i] = fminf(fminf(racc1[i], a0[i]), a1[i]);
        }
    }

    // Row-min across the 32 cols (lanes of each half) for both tiles.
    #pragma unroll
    for (int i = 0; i < 16; ++i) {
        float v0 = racc0[i], v1 = racc1[i];
        v0 = fminf(v0, __shfl_xor(v0, 16, 64));
        v1 = fminf(v1, __shfl_xor(v1, 16, 64));
        v0 = fminf(v0, __shfl_xor(v0,  8, 64));
        v1 = fminf(v1, __shfl_xor(v1,  8, 64));
        v0 = fminf(v0, __shfl_xor(v0,  4, 64));
        v1 = fminf(v1, __shfl_xor(v1,  4, 64));
        v0 = fminf(v0, __shfl_xor(v0,  2, 64));
        v1 = fminf(v1, __shfl_xor(v1,  2, 64));
        v0 = fminf(v0, __shfl_xor(v0,  1, 64));
        v1 = fminf(v1, __shfl_xor(v1,  1, 64));
        racc0[i] = v0;
        racc1[i] = v1;
    }

    if (l31 == 0) {
        const int base = qblk + r0;
        #pragma unroll
        for (int i = 0; i < 16; ++i) {
            const int row = (i & 3) + 8 * (i >> 2) + 4 * half;  // m74/m101 C/D map
            atomicMin(&mins_u[base + row],      enc_f32(racc0[i]));
            atomicMin(&mins_u[base + 32 + row], enc_f32(racc1[i]));
        }
    }

    __syncthreads();   // before re-staging ldsB in the next rep
    }  // rep
}

// Finish: mins hold complete d. sqrt, block-reduce, one atomicAdd.
__global__ __launch_bounds__(256) void chamfer_finish(
    const unsigned* __restrict__ mins_u, float* __restrict__ out, int N)
{
    const int tid = threadIdx.x;
    const int qi = blockIdx.x * 256 + tid;

    float v = sqrtf(fmaxf(dec_f32(mins_u[qi]), 0.0f));

    for (int off = 32; off > 0; off >>= 1) v += __shfl_down(v, off, 64);
    __shared__ float wsum[4];
    if ((tid & 63) == 0) wsum[tid >> 6] = v;
    __syncthreads();
    if (tid == 0) {
        const float bsum = wsum[0] + wsum[1] + wsum[2] + wsum[3];
        atomicAdd(out, bsum * 5.0f / (float)N);  // (mean1+mean2)*0.5*10
    }
}

extern "C" void kernel_launch(void* const* d_in, const int* in_sizes, int n_in,
                              void* d_out, int out_size, void* d_ws, size_t ws_size,
                              hipStream_t stream)
{
    const float* state_x = (const float*)d_in[0];
    const float* target  = (const float*)d_in[1];
    float* out = (float*)d_out;

    const int N = in_sizes[0] / 3;               // 16384
    const int twoN = 2 * N;

    int S = S_SLICES;
    while (S > 1 && (N % (S * 64)) != 0) S >>= 1;

    // Workspace: mins (2N u32) | AfragS | AfragT | BfragS | BfragT (512KB each).
    char* wsb = (char*)d_ws;
    unsigned* mins_u = (unsigned*)wsb;
    uint4* AfragS = (uint4*)(wsb + (size_t)twoN * 4);
    uint4* AfragT = (uint4*)(wsb + (size_t)twoN * 4 + (size_t)N * 32);
    uint4* BfragS = (uint4*)(wsb + (size_t)twoN * 4 + (size_t)N * 64);
    uint4* BfragT = (uint4*)(wsb + (size_t)twoN * 4 + (size_t)N * 96);

    chamfer_prep<<<twoN / 256, 256, 0, stream>>>(
        state_x, target, AfragS, AfragT, BfragS, BfragT, mins_u, out, N);

    const int rowBlocks = twoN / 256;            // 128 blocks of 256 rows
    chamfer_main<<<rowBlocks * S, 256, 0, stream>>>(
        (const bf16x8*)AfragS, (const bf16x8*)AfragT,
        (const bf16x8*)BfragS, (const bf16x8*)BfragT, mins_u, N, S);

    chamfer_finish<<<twoN / 256, 256, 0, stream>>>(mins_u, out, N);
}

// Round 6
// 79.942 us; speedup vs baseline: 1.6150x; 1.6150x over previous
//
#include <hip/hip_runtime.h>
#include <math.h>

// Chamfer loss, two 16384x3 fp32 clouds.
// R10: R9 diagnostic showed in-kernel dilation (rep x2 = 81.4us, work-
// proportional): MfmaUtil 17 vs VALUBusy 75, VGPR=72 (accs in AGPRs ->
// accvgpr read/write churn ~5x the min3 work), LDS_BANK_CONFLICT = 4 extra
// cyc per ds_read_b128, 320-op shuffle epilogue. Fixes:
//  (a) inline-asm v_mfma with "v" constraints -> accumulators in VGPRs,
//      min3 folds read MFMA dests directly (no accvgpr ops, no C re-init).
//      Hazard: 4 MFMAs issued back-to-back, then sched_barrier + s_nop 7 +
//      sched_barrier before any dest read (>=24 cyc gap, rule #18 fence).
//  (b) B-fragments pre-ordered [g64][tile32][half][col32] in prep -> each
//      ds_read_b128 is a contiguous 1024B wave read, conflict-free.
//  (c) epilogue: LDS transpose-reduce (reuse ldsB, cg-XOR swizzle) instead
//      of 320 shuffle ops; one atomicMin per thread.

typedef __attribute__((ext_vector_type(8)))  short bf16x8;   // 8 bf16 = 4 VGPR
typedef __attribute__((ext_vector_type(16))) float f32x16;   // MFMA C/D

#define S_SLICES 16   // col slices per direction; C = N/S = 1024 (32 KB LDS)

// Monotone float->uint map: a<b  <=>  enc(a)<enc(b).
__device__ __forceinline__ unsigned enc_f32(float f) {
    int b = __float_as_int(f);
    return (b >= 0) ? ((unsigned)b | 0x80000000u) : ~(unsigned)b;
}
__device__ __forceinline__ float dec_f32(unsigned k) {
    int b = (k & 0x80000000u) ? (int)(k & 0x7FFFFFFFu) : ~(int)k;
    return __int_as_float(b);
}

// fp32 -> bf16 (RNE), and back.
__device__ __forceinline__ unsigned short f2bf(float v) {
    unsigned u = __float_as_uint(v);
    u += 0x7FFFu + ((u >> 16) & 1u);
    return (unsigned short)(u >> 16);
}
__device__ __forceinline__ float bf2f(unsigned short b) {
    unsigned u = ((unsigned)b) << 16;
    return __uint_as_float(u);
}
__device__ __forceinline__ unsigned pk2(unsigned short lo, unsigned short hi) {
    return (unsigned)lo | ((unsigned)hi << 16);
}

__device__ __forceinline__ f32x16 mfma_v(bf16x8 a, bf16x8 b, f32x16 c) {
    f32x16 d;
    asm("v_mfma_f32_32x32x16_bf16 %0, %1, %2, %3"
        : "=&v"(d) : "v"(a), "v"(b), "v"(c));
    return d;
}

// Build A-role and B-role K=16 fragments for every point of both clouds.
// d = |q|^2 + |p|^2 - 2(qh+ql).(ph+pl), all cross terms in the 16 K slots.
// B-role fragments are scattered into LDS-friendly order:
//   pos(col j, half h) = (j>>6)*128 + ((j>>5)&1)*64 + h*32 + (j&31).
__global__ __launch_bounds__(256) void chamfer_prep(
    const float* __restrict__ state_x, const float* __restrict__ target,
    uint4* __restrict__ AfragS, uint4* __restrict__ AfragT,
    uint4* __restrict__ BfragS, uint4* __restrict__ BfragT,
    unsigned* __restrict__ mins_u, float* __restrict__ out, int N)
{
    const int p = blockIdx.x * 256 + threadIdx.x;     // [0, 2N)
    const float* src = (p < N) ? state_x : target;
    const int i = (p < N) ? p : p - N;

    const float x = src[3*i+0], y = src[3*i+1], z = src[3*i+2];
    const float n2 = fmaf(x, x, fmaf(y, y, z * z));

    const unsigned short hx = f2bf(x), hy = f2bf(y), hz = f2bf(z);
    const unsigned short lx = f2bf(x - bf2f(hx));
    const unsigned short ly = f2bf(y - bf2f(hy));
    const unsigned short lz = f2bf(z - bf2f(hz));
    const unsigned short mhx = f2bf(-2.0f*x), mhy = f2bf(-2.0f*y), mhz = f2bf(-2.0f*z);
    const unsigned short mlx = f2bf(-2.0f*x - bf2f(mhx));
    const unsigned short mly = f2bf(-2.0f*y - bf2f(mhy));
    const unsigned short mlz = f2bf(-2.0f*z - bf2f(mhz));
    const unsigned short hn = f2bf(n2);
    const unsigned short ln = f2bf(n2 - bf2f(hn));
    const unsigned short ONE = 0x3F80;

    // A-role: [mh(3), ml(3), mh(3), ml(3), hn, ln, 1, 1]
    uint4 A0 = make_uint4(pk2(mhx,mhy), pk2(mhz,mlx), pk2(mly,mlz), pk2(mhx,mhy));
    uint4 A1 = make_uint4(pk2(mhz,mlx), pk2(mly,mlz), pk2(hn,ln),   pk2(ONE,ONE));
    // B-role: [h(3), h(3), l(3), l(3), 1, 1, hn, ln]
    uint4 B0 = make_uint4(pk2(hx,hy), pk2(hz,hx), pk2(hy,hz), pk2(lx,ly));
    uint4 B1 = make_uint4(pk2(lz,lx), pk2(ly,lz), pk2(ONE,ONE), pk2(hn,ln));

    uint4* Aarr = (p < N) ? AfragS : AfragT;
    uint4* Barr = (p < N) ? BfragS : BfragT;
    Aarr[2*i+0] = A0;  Aarr[2*i+1] = A1;

    const int bbase = (i >> 6) * 128 + ((i >> 5) & 1) * 64 + (i & 31);
    Barr[bbase +  0] = B0;   // half 0
    Barr[bbase + 32] = B1;   // half 1

    mins_u[p] = 0xFFFFFFFFu;
    if (p == 0) *out = 0.0f;
}

// Main: block = 4 waves x 64 rows = 256 query rows, one 1024-col slice of
// the DB staged in LDS (32 KB). Per iter: 2 contiguous ds_read_b128,
// 4 VGPR-form MFMAs, 32 min3. LDS transpose-reduce epilogue.
__global__ __launch_bounds__(256) void chamfer_main(
    const bf16x8* __restrict__ AfragS, const bf16x8* __restrict__ AfragT,
    const bf16x8* __restrict__ BfragS, const bf16x8* __restrict__ BfragT,
    unsigned* __restrict__ mins_u, int N, int S)
{
    const int tid  = threadIdx.x;
    const int lane = tid & 63;
    const int l31  = lane & 31;
    const int half = lane >> 5;
    const int w    = tid >> 6;

    const int bs = blockIdx.x / S;            // row-block (256 rows)
    const int s  = blockIdx.x % S;            // col slice
    const int qblk = bs * 256;                // [0, 2N), never straddles N

    const bf16x8* afr;
    const bf16x8* bfr;
    if (qblk < N) { afr = AfragT + (size_t)qblk * 2;       bfr = BfragS; }
    else          { afr = AfragS + (size_t)(qblk - N) * 2; bfr = BfragT; }

    const int C = N / S;                      // 1024 cols per slice

    // ---- stage the B slice into LDS (2048 uint4 = 32 KB), identity copy ----
    __shared__ uint4 ldsB[2048];
    {
        const uint4* src = (const uint4*)bfr + (size_t)(s * C) * 2;
        #pragma unroll
        for (int j = 0; j < 8; ++j)
            ldsB[tid + j * 256] = src[tid + j * 256];
    }
    __syncthreads();
    const bf16x8* lb = (const bf16x8*)ldsB;

    // A fragments for this wave's two 32-row tiles (rows w*64 .. w*64+63).
    const int r0 = w * 64;
    const bf16x8 av0 = afr[(r0 +      l31) * 2 + half];
    const bf16x8 av1 = afr[(r0 + 32 + l31) * 2 + half];

    // B read offset: contiguous per wave: pos = it*128 + tile*64 + half*32 + l31.
    const int boff = half * 32 + l31;

    f32x16 racc0, racc1, zc;
    #pragma unroll
    for (int i = 0; i < 16; ++i) { racc0[i] = 3.0e38f; racc1[i] = 3.0e38f; zc[i] = 0.0f; }

    #pragma unroll 2
    for (int it = 0; it < C / 64; ++it) {
        const bf16x8 b0 = lb[it * 128 + boff];        // cols it*64    + l31 (1024B contiguous)
        const bf16x8 b1 = lb[it * 128 + 64 + boff];   // cols it*64+32 + l31
        f32x16 a0 = mfma_v(av0, b0, zc);
        f32x16 a1 = mfma_v(av0, b1, zc);
        f32x16 a2 = mfma_v(av1, b0, zc);
        f32x16 a3 = mfma_v(av1, b1, zc);
        __builtin_amdgcn_sched_barrier(0);
        asm volatile("s_nop 7");                      // MFMA->VALU read gap
        __builtin_amdgcn_sched_barrier(0);
        #pragma unroll
        for (int i = 0; i < 16; ++i)
            racc0[i] = fminf(fminf(racc0[i], a0[i]), a1[i]);   // v_min3
        #pragma unroll
        for (int i = 0; i < 16; ++i)
            racc1[i] = fminf(fminf(racc1[i], a2[i]), a3[i]);
    }

    // ---- epilogue: LDS transpose-reduce (reuse ldsB) ----
    __syncthreads();                               // all waves done with ldsB
    float* lf = (float*)ldsB;                      // 8192 floats = 4 areas x [64][32]
    const int cg = l31 >> 2, cl = l31 & 3;
    #pragma unroll
    for (int i = 0; i < 16; ++i) {
        const int row0 = (i & 3) + 8 * (i >> 2) + 4 * half;   // m74/m101 C/D map
        const int row1 = row0 + 32;
        lf[w * 2048 + row0 * 32 + ((cg ^ (row0 & 7)) << 2) + cl] = racc0[i];
        lf[w * 2048 + row1 * 32 + ((cg ^ (row1 & 7)) << 2) + cl] = racc1[i];
    }
    __syncthreads();
    {
        const int r = tid & 63, wr = tid >> 6;     // thread <-> block row
        const float4* rowp = (const float4*)(lf + wr * 2048 + r * 32);
        float m0 = 3.0e38f, m1 = 3.0e38f;
        #pragma unroll
        for (int g = 0; g < 8; g += 2) {
            const float4 v0 = rowp[g ^ (r & 7)];
            const float4 v1 = rowp[(g + 1) ^ (r & 7)];
            m0 = fminf(fminf(m0, v0.x), fminf(v0.y, v0.z));
            m0 = fminf(m0, v0.w);
            m1 = fminf(fminf(m1, v1.x), fminf(v1.y, v1.z));
            m1 = fminf(m1, v1.w);
        }
        atomicMin(&mins_u[qblk + wr * 64 + r], enc_f32(fminf(m0, m1)));
    }
}

// Finish: mins hold complete d. sqrt, block-reduce, one atomicAdd.
__global__ __launch_bounds__(256) void chamfer_finish(
    const unsigned* __restrict__ mins_u, float* __restrict__ out, int N)
{
    const int tid = threadIdx.x;
    const int qi = blockIdx.x * 256 + tid;

    float v = sqrtf(fmaxf(dec_f32(mins_u[qi]), 0.0f));

    for (int off = 32; off > 0; off >>= 1) v += __shfl_down(v, off, 64);
    __shared__ float wsum[4];
    if ((tid & 63) == 0) wsum[tid >> 6] = v;
    __syncthreads();
    if (tid == 0) {
        const float bsum = wsum[0] + wsum[1] + wsum[2] + wsum[3];
        atomicAdd(out, bsum * 5.0f / (float)N);  // (mean1+mean2)*0.5*10
    }
}

extern "C" void kernel_launch(void* const* d_in, const int* in_sizes, int n_in,
                              void* d_out, int out_size, void* d_ws, size_t ws_size,
                              hipStream_t stream)
{
    const float* state_x = (const float*)d_in[0];
    const float* target  = (const float*)d_in[1];
    float* out = (float*)d_out;

    const int N = in_sizes[0] / 3;               // 16384
    const int twoN = 2 * N;

    int S = S_SLICES;
    while (S > 1 && (N % (S * 64)) != 0) S >>= 1;

    // Workspace: mins (2N u32) | AfragS | AfragT | BfragS | BfragT (512KB each).
    char* wsb = (char*)d_ws;
    unsigned* mins_u = (unsigned*)wsb;
    uint4* AfragS = (uint4*)(wsb + (size_t)twoN * 4);
    uint4* AfragT = (uint4*)(wsb + (size_t)twoN * 4 + (size_t)N * 32);
    uint4* BfragS = (uint4*)(wsb + (size_t)twoN * 4 + (size_t)N * 64);
    uint4* BfragT = (uint4*)(wsb + (size_t)twoN * 4 + (size_t)N * 96);

    chamfer_prep<<<twoN / 256, 256, 0, stream>>>(
        state_x, target, AfragS, AfragT, BfragS, BfragT, mins_u, out, N);

    const int rowBlocks = twoN / 256;            // 128 blocks of 256 rows
    chamfer_main<<<rowBlocks * S, 256, 0, stream>>>(
        (const bf16x8*)AfragS, (const bf16x8*)AfragT,
        (const bf16x8*)BfragS, (const bf16x8*)BfragT, mins_u, N, S);

    chamfer_finish<<<twoN / 256, 256, 0, stream>>>(mins_u, out, N);
}